// Round 1
// 105.129 us; speedup vs baseline: 1.0529x; 1.0529x over previous
//
#include <hip/hip_runtime.h>
#include <math.h>

// ---------------------------------------------------------------------------
// CategoricalAwareTabularEncoder — design 3 (b128-packed LDS, 1024 thr/block)
//
// Key algebra (unchanged): pair-MLP layer-1 factorizes:
//   pairs(i,j)@W1 = emb_i@W1a + emb_j@W1b
//   U = emb@W1a + b1, V = emb@W1b, Hsum[d] = sum_{i<j} relu(U_i[d]+V_j[d]),
//   combo_sum = Hsum@W2 + P*b2.
//
// Design-3 changes vs design-2 (all LDS-issue-count reductions):
//  * Weights packed interleaved: WUV as h8 {Wu_lo,Wu_hi,Wv_lo,Wv_hi} per
//    (k4,d) -> one ds_read_b128; WF as h4 -> one ds_read_b64.  Phase A reads
//    E as b128 covering two k4 slices.  160 -> 64 LDS instrs per thread.
//  * V stored transposed [d2][j] stride 66 (2-way bank alias = free) so
//    phase B reads b64 pairs of j instead of 63 scalar b32.
//  * FHT row stride 34 (even -> b64-aligned) and freq_w2 packed [f][d2] so
//    phase C does 8 b64 + 4 b128-broadcast instead of 64 b32 per thread.
//  * Hsum reduce + combo_sum fused into wave 0 via __shfl_xor butterfly:
//    one fewer __syncthreads and no HS LDS round-trip.
// ---------------------------------------------------------------------------

typedef _Float16 h2 __attribute__((ext_vector_type(2)));
typedef _Float16 h4 __attribute__((ext_vector_type(4)));
typedef _Float16 h8 __attribute__((ext_vector_type(8)));
union H4u { h4 v; h2 h[2]; };
union H8u { h8 v; h2 h[4]; };

constexpr int BATCH = 256;
constexpr int S = 64, D = 64, F = 10;
constexpr int NPAIR = S * (S - 1) / 2;  // 2016

// LDS map in 4-byte units (total 16128 u32 = 64512 B <= 64 KB)
//   WUV  h8 [k4*64+d] {wu_lo,wu_hi,wv_lo,wv_hi}   @0     (4096 u32)
//   WF   h4 [k4*64+d] {wf_lo,wf_hi}               @4096  (2048 u32)
//   After phase A the weight region is dead -> aliased:
//     PART f32 [32 g][64 d] @0..2047 | FF f32 [64][10] @2048..2687
//     CS f32 @2752..2761
constexpr int EMBS = 6144;   // [s][k2] h2, stride 32 (2048 u32)
constexpr int U2B  = 8192;   // [s][d2] h2, stride 32 (2048 u32)
constexpr int V2T  = 10240;  // [d2][j] h2, stride 66 (2112 u32)
constexpr int FHT  = 12352;  // [s][d2] h2, stride 34 (2176 u32); aliases EMBT
constexpr int EMBT = 12352;  // [k2][s] h2 (2048 u32), dead after cluster phase
constexpr int CF_F = 14528;  // f32 [64][10] cluster softmax (640)
constexpr int DI_F = 15168;  // f32 [64][10] distances (640)
constexpr int W2P  = 15808;  // [f*32+d2] h2 packed freq_w2 (320)
constexpr int PART_F = 0;
constexpr int FF_F   = 2048;
constexpr int CS_F   = 2752;

__device__ __forceinline__ h2 pk2(float a, float b) {
#if __has_builtin(__builtin_amdgcn_cvt_pkrtz)
  auto t = __builtin_amdgcn_cvt_pkrtz(a, b);
  return __builtin_bit_cast(h2, t);
#else
  h2 r; r.x = (_Float16)a; r.y = (_Float16)b; return r;
#endif
}

__device__ __forceinline__ float fdot2f(h2 a, h2 b, float c) {
#if __has_builtin(__builtin_amdgcn_fdot2)
  typedef __fp16 q2 __attribute__((ext_vector_type(2)));
  return __builtin_amdgcn_fdot2(__builtin_bit_cast(q2, a),
                                __builtin_bit_cast(q2, b), c, false);
#else
  return c + (float)a.x * (float)b.x + (float)a.y * (float)b.y;
#endif
}

__device__ __forceinline__ h2 hmax2z(h2 a) {  // elementwise max(a, 0)
#if __has_builtin(__builtin_elementwise_max)
  h2 z = {(_Float16)0, (_Float16)0};
  return __builtin_elementwise_max(a, z);
#else
  h2 r;
  r.x = a.x > (_Float16)0 ? a.x : (_Float16)0;
  r.y = a.y > (_Float16)0 ? a.y : (_Float16)0;
  return r;
#endif
}

// value of lane (l+1) for even lanes l, via quad_perm [1,1,3,3]
__device__ __forceinline__ float lane_up1(float v) {
#if __has_builtin(__builtin_amdgcn_update_dpp)
  int r = __builtin_amdgcn_update_dpp(0, __float_as_int(v), 0xF5, 0xF, 0xF, false);
  return __int_as_float(r);
#else
  return __shfl_down(v, 1, 64);
#endif
}

__global__ __launch_bounds__(1024, 4)
void cat_enc_kernel(const int*   __restrict__ ids,
                    const float* __restrict__ emb_table,
                    const float* __restrict__ comb_w1,
                    const float* __restrict__ comb_b1,
                    const float* __restrict__ comb_w2,
                    const float* __restrict__ comb_b2,
                    const float* __restrict__ freq_w1,
                    const float* __restrict__ freq_b1,
                    const float* __restrict__ freq_w2,
                    const float* __restrict__ freq_b2,
                    const float* __restrict__ centers,
                    const float* __restrict__ cat_freq,
                    const float* __restrict__ total_samples,
                    float*       __restrict__ out)
{
  __shared__ __align__(16) unsigned int ldsu[16128];
  h2*    ldsH = (h2*)ldsu;
  float* ldsf = (float*)ldsu;
  const int tid = threadIdx.x;
  const int b = blockIdx.x, bBase = b * S;

  // ---------------- stage: gather emb (both layouts) + pack weights ---------
  {
    // emb gather first: dependent-load chain (ids -> row), start it early
    int s = tid >> 4, q = tid & 15;
    int id = ids[bBase + s];
    float4 e4 = *(const float4*)(emb_table + (size_t)id * D + q * 4);
    h2 p0 = pk2(e4.x, e4.y), p1 = pk2(e4.z, e4.w);
    ldsH[EMBS + s * 32 + q * 2]     = p0;
    ldsH[EMBS + s * 32 + q * 2 + 1] = p1;
    ldsH[EMBT + (q * 2) * 64 + s]     = p0;
    ldsH[EMBT + (q * 2 + 1) * 64 + s] = p1;

    // weight pack: e == tid enumerates (k4 = tid>>6, dd = tid&63)
    {
      const int k4 = tid >> 6, dd = tid & 63;
      const float* s0p = comb_w1 + (k4 * 4) * D + dd;        // Wu cols
      const float* s1p = s0p + D * D;                        // Wv cols
      const float* s2p = freq_w1 + (k4 * 4) * D + dd;        // Wf cols
      h4* dst = (h4*)ldsu;
      H4u u0; u0.h[0] = pk2(s0p[0], s0p[D]); u0.h[1] = pk2(s0p[2 * D], s0p[3 * D]);
      H4u u1; u1.h[0] = pk2(s1p[0], s1p[D]); u1.h[1] = pk2(s1p[2 * D], s1p[3 * D]);
      H4u u2; u2.h[0] = pk2(s2p[0], s2p[D]); u2.h[1] = pk2(s2p[2 * D], s2p[3 * D]);
      dst[2 * tid]     = u0.v;     // WUV elem tid, u-half
      dst[2 * tid + 1] = u1.v;     // WUV elem tid, v-half
      dst[2048 + tid]  = u2.v;     // WF elem tid
    }
    if (tid < 320) {
      int f = tid >> 5, d2 = tid & 31;
      ldsH[W2P + tid] = pk2(freq_w2[(2 * d2) * F + f], freq_w2[(2 * d2 + 1) * F + f]);
    }
  }
  __syncthreads();

  // ---------------- cluster distances: wave c (0..9) does center c ----------
  {
    int wv = __builtin_amdgcn_readfirstlane((int)(tid >> 6));
    int lane = tid & 63;
    if (wv < 10) {
      const float* crow = centers + wv * D;  // uniform -> s_load
      float acc = 0.f;
#pragma unroll 8
      for (int k2 = 0; k2 < 32; ++k2) {
        h2 e2 = ldsH[EMBT + k2 * 64 + lane];        // stride-1 lanes, conflict-free
        float t0 = (float)e2.x - crow[2 * k2];
        float t1 = (float)e2.y - crow[2 * k2 + 1];
        acc = fmaf(t0, t0, fmaf(t1, t1, acc));
      }
      ldsf[DI_F + lane * 10 + wv] = sqrtf(acc);
    }
  }
  __syncthreads();  // FHT (phase A) overwrites EMBT

  // ---------------- phase A: U,V,FH for 4 tokens per wave, lane = d ---------
  {
    const int d  = tid & 63;
    const int wv = __builtin_amdgcn_readfirstlane((int)(tid >> 6));
    const int s0 = wv * 4;
    const float invT = 1.0f / total_samples[0];
    int idv[4];
#pragma unroll
    for (int si = 0; si < 4; ++si)
      idv[si] = __builtin_amdgcn_readfirstlane(ids[bBase + s0 + si]);
    const float b1d = comb_b1[d], fb1d = freq_b1[d], fw1L = freq_w1[D * D + d];
    float aU[4], aV[4], aF[4];
#pragma unroll
    for (int si = 0; si < 4; ++si) {
      aU[si] = b1d; aV[si] = 0.f;
      aF[si] = fmaf(cat_freq[idv[si]] * invT, fw1L, fb1d);
    }
    const h8* WUVp = (const h8*)ldsu;           // elem (k4*64+d), 16 B
    const h4* WFp  = (const h4*)(ldsu + 4096);  // elem (k4*64+d), 8 B
#pragma unroll 2
    for (int k8 = 0; k8 < 8; ++k8) {
      const int k4a = 2 * k8, k4b = 2 * k8 + 1;
      H8u wa; wa.v = WUVp[k4a * 64 + d];        // ds_read_b128
      H8u wb; wb.v = WUVp[k4b * 64 + d];
      H4u fa; fa.v = WFp[k4a * 64 + d];         // ds_read_b64
      H4u fb; fb.v = WFp[k4b * 64 + d];
#pragma unroll
      for (int si = 0; si < 4; ++si) {
        H8u e; e.v = *(const h8*)&ldsH[EMBS + (s0 + si) * 32 + k8 * 4];  // b128 bcast
        aU[si] = fdot2f(e.h[0], wa.h[0], aU[si]);
        aU[si] = fdot2f(e.h[1], wa.h[1], aU[si]);
        aV[si] = fdot2f(e.h[0], wa.h[2], aV[si]);
        aV[si] = fdot2f(e.h[1], wa.h[3], aV[si]);
        aF[si] = fdot2f(e.h[0], fa.h[0], aF[si]);
        aF[si] = fdot2f(e.h[1], fa.h[1], aF[si]);
        aU[si] = fdot2f(e.h[2], wb.h[0], aU[si]);
        aU[si] = fdot2f(e.h[3], wb.h[1], aU[si]);
        aV[si] = fdot2f(e.h[2], wb.h[2], aV[si]);
        aV[si] = fdot2f(e.h[3], wb.h[3], aV[si]);
        aF[si] = fdot2f(e.h[2], fb.h[0], aF[si]);
        aF[si] = fdot2f(e.h[3], fb.h[1], aF[si]);
      }
    }
    // pack (d, d+1) pairs across even/odd lanes, store f16x2
    const bool evenl = ((d & 1) == 0);
    const int d2 = d >> 1;
#pragma unroll
    for (int si = 0; si < 4; ++si) {
      float un = lane_up1(aU[si]);
      float vn = lane_up1(aV[si]);
      float fh = fmaxf(aF[si], 0.f);
      float fn = lane_up1(fh);
      if (evenl) {
        int srow = s0 + si;
        ldsH[U2B + srow * 32 + d2] = pk2(aU[si], un);
        ldsH[V2T + d2 * 66 + srow] = pk2(aV[si], vn);  // transposed V
        ldsH[FHT + srow * 34 + d2] = pk2(fh, fn);
      }
    }
  }
  __syncthreads();

  // ------- phase C (waves 0..9: freq_feat) + softmax (wave 10) --------------
  {
    if (tid < 640) {
      int s = tid & 63;
      int f = __builtin_amdgcn_readfirstlane((int)(tid >> 6));  // wave = f
      float acc = freq_b2[f];
      const h8* wrow = (const h8*)&ldsH[W2P + f * 32];
#pragma unroll
      for (int d8 = 0; d8 < 4; ++d8) {
        H8u wf; wf.v = wrow[d8];                                  // b128 bcast
        H4u f0; f0.v = *(const h4*)&ldsH[FHT + s * 34 + d8 * 4];      // b64
        H4u f1; f1.v = *(const h4*)&ldsH[FHT + s * 34 + d8 * 4 + 2];  // b64
        acc = fdot2f(f0.h[0], wf.h[0], acc);
        acc = fdot2f(f0.h[1], wf.h[1], acc);
        acc = fdot2f(f1.h[0], wf.h[2], acc);
        acc = fdot2f(f1.h[1], wf.h[3], acc);
      }
      ldsf[FF_F + s * 10 + f] = acc;
    } else if (tid < 704) {
      int s = tid - 640;
      float dv[10], dmin = 1e30f;
#pragma unroll
      for (int c = 0; c < 10; ++c) { dv[c] = ldsf[DI_F + s * 10 + c]; dmin = fminf(dmin, dv[c]); }
      float p[10], sum = 0.f;
#pragma unroll
      for (int c = 0; c < 10; ++c) { p[c] = expf(dmin - dv[c]); sum += p[c]; }
      float rs = 1.0f / sum;
#pragma unroll
      for (int c = 0; c < 10; ++c) ldsf[CF_F + s * 10 + c] = p[c] * rs;
    }
  }

  // ------- phase B: Hsum partials, group g owns rows {g, 63-g} --------------
  {
    const int dg = tid & 31, g = tid >> 5;
    h2 u2a = ldsH[U2B + g * 32 + dg];
    h2 u2b = ldsH[U2B + (63 - g) * 32 + dg];
    h2 za = {(_Float16)0, (_Float16)0};
    h2 acA0 = za, acA1 = za, accb = za;
    const int jsplit = 64 - g;      // row-b active for j >= jsplit (never in head)
    int j = g + 1;
    if (j & 1) {                    // scalar head to even j
      h2 v2 = ldsH[V2T + dg * 66 + j];
      acA0 = acA0 + hmax2z(u2a + v2);
      ++j;
    }
#pragma unroll 4
    for (; j < 64; j += 2) {
      H4u v; v.v = *(const h4*)&ldsH[V2T + dg * 66 + j];   // b64: j, j+1
      acA0 = acA0 + hmax2z(u2a + v.h[0]);
      acA1 = acA1 + hmax2z(u2a + v.h[1]);
      if (j + 1 >= jsplit) {
        if (j >= jsplit) accb = accb + hmax2z(u2b + v.h[0]);
        accb = accb + hmax2z(u2b + v.h[1]);
      }
    }
    h2 at = acA0 + acA1 + accb;
    ldsf[PART_F + g * 64 + 2 * dg]     = (float)at.x;
    ldsf[PART_F + g * 64 + 2 * dg + 1] = (float)at.y;
  }
  __syncthreads();

  // ------- Hsum reduce + combo_sum fused (wave 0, butterfly) ----------------
  if (tid < 64) {
    float h = 0.f;
#pragma unroll
    for (int g2 = 0; g2 < 32; ++g2) h += ldsf[PART_F + g2 * 64 + tid];
    float csv = 0.f;
#pragma unroll
    for (int f = 0; f < 10; ++f) {
      float p = h * comb_w2[tid * F + f];
#pragma unroll
      for (int off = 1; off < 64; off <<= 1) p += __shfl_xor(p, off, 64);
      if (tid == f) csv = p;
    }
    if (tid < 10) ldsf[CS_F + tid] = fmaf(comb_b2[tid], (float)NPAIR, csv);
  }
  __syncthreads();

  // ------- epilogue ---------------------------------------------------------
  if (tid < 640) {
    int f = tid % 10;
    float val = (ldsf[FF_F + tid] + ldsf[CS_F + f] + ldsf[CF_F + tid])
              * (1.0f / (float)(NPAIR + 2));
    out[(size_t)b * 640 + tid] = val;
  }
}

extern "C" void kernel_launch(void* const* d_in, const int* in_sizes, int n_in,
                              void* d_out, int out_size, void* d_ws, size_t ws_size,
                              hipStream_t stream) {
  (void)in_sizes; (void)n_in; (void)d_ws; (void)ws_size; (void)out_size;
  const int*   ids        = (const int*)  d_in[0];
  const float* emb_table  = (const float*)d_in[1];
  const float* comb_w1    = (const float*)d_in[2];
  const float* comb_b1    = (const float*)d_in[3];
  const float* comb_w2    = (const float*)d_in[4];
  const float* comb_b2    = (const float*)d_in[5];
  const float* freq_w1    = (const float*)d_in[6];
  const float* freq_b1    = (const float*)d_in[7];
  const float* freq_w2    = (const float*)d_in[8];
  const float* freq_b2    = (const float*)d_in[9];
  const float* centers    = (const float*)d_in[10];
  const float* cat_freq   = (const float*)d_in[11];
  const float* total_samp = (const float*)d_in[12];
  float* out = (float*)d_out;

  hipLaunchKernelGGL(cat_enc_kernel, dim3(BATCH), dim3(1024), 0, stream,
                     ids, emb_table, comb_w1, comb_b1, comb_w2, comb_b2,
                     freq_w1, freq_b1, freq_w2, freq_b2, centers, cat_freq,
                     total_samp, out);
}